// Round 13
// baseline (123.401 us; speedup 1.0000x reference)
//
#include <hip/hip_runtime.h>
#include <hip/hip_bf16.h>

typedef __attribute__((ext_vector_type(8))) short bf16x8;
typedef __attribute__((ext_vector_type(4))) float f32x4;
typedef __attribute__((ext_vector_type(16))) float f32x16;

#define B_ 2
#define S_ 2048
#define D_ 1024
#define H_ 16

__device__ __forceinline__ unsigned short f2bf(float x) {
  unsigned u = __float_as_uint(x);
  unsigned r = (u + 0x7fffu + ((u >> 16) & 1u)) >> 16;
  return (unsigned short)r;
}

__device__ __forceinline__ float bf2f(unsigned short x) {
  return __uint_as_float((unsigned)x << 16);
}

__device__ __forceinline__ unsigned cvt_pk_bf16(float lo, float hi) {
  unsigned r;
  asm("v_cvt_pk_bf16_f32 %0, %1, %2" : "=v"(r) : "v"(lo), "v"(hi));
  return r;
}

__device__ __forceinline__ void gload_lds16(const void* g, void* l) {
  __builtin_amdgcn_global_load_lds((const __attribute__((address_space(1))) void*)g,
                                   (__attribute__((address_space(3))) void*)l, 16, 0, 0);
}

// counted-vmcnt barrier: leave N loads in flight across the barrier (T4).
#define VM_BARRIER(N) do {                                   \
    asm volatile("s_waitcnt vmcnt(" #N ")" ::: "memory");    \
    __builtin_amdgcn_s_barrier();                            \
    __builtin_amdgcn_sched_barrier(0);                       \
  } while (0)

// ---------------- prep: bf16 convert (q, ctx) + 4 weight transposes, one launch ----------------
__global__ __launch_bounds__(256) void prep_kernel(const float* __restrict__ query,
                                                   const float* __restrict__ ctx,
                                                   const float* __restrict__ Wq, const float* __restrict__ Wk,
                                                   const float* __restrict__ Wv, const float* __restrict__ Wo,
                                                   unsigned short* __restrict__ qb, unsigned short* __restrict__ cb,
                                                   unsigned short* __restrict__ WqT, unsigned short* __restrict__ WkT,
                                                   unsigned short* __restrict__ WvT, unsigned short* __restrict__ WoT) {
  __shared__ float tile[32][33];
  int bid = blockIdx.x;
  if (bid < 8192) {
    const float* s = bid < 4096 ? query : ctx;
    unsigned short* d = bid < 4096 ? qb : cb;
    int i = (bid & 4095) * 256 + threadIdx.x;
    float4 v = ((const float4*)s)[i];
    ushort4 o;
    o.x = f2bf(v.x); o.y = f2bf(v.y); o.z = f2bf(v.z); o.w = f2bf(v.w);
    ((ushort4*)d)[i] = o;
    return;
  }
  int tid = bid - 8192;              // 4096 transpose blocks
  int z = tid >> 10, r = tid & 1023;
  const float* W; unsigned short* WT;
  if (z == 0)      { W = Wq; WT = WqT; }
  else if (z == 1) { W = Wk; WT = WkT; }
  else if (z == 2) { W = Wv; WT = WvT; }
  else             { W = Wo; WT = WoT; }
  int r0 = (r >> 5) * 32, c0 = (r & 31) * 32;
  int t = threadIdx.x;
  int lr = t >> 3, lc = (t & 7) * 4;
  float4 v = *(const float4*)&W[(size_t)(r0 + lr) * 1024 + c0 + lc];
  tile[lr][lc + 0] = v.x; tile[lr][lc + 1] = v.y; tile[lr][lc + 2] = v.z; tile[lr][lc + 3] = v.w;
  __syncthreads();
  ushort4 o;
  o.x = f2bf(tile[lc + 0][lr]);
  o.y = f2bf(tile[lc + 1][lr]);
  o.z = f2bf(tile[lc + 2][lr]);
  o.w = f2bf(tile[lc + 3][lr]);
  *(ushort4*)&WT[(size_t)(c0 + lr) * 1024 + r0 + lc] = o;
}

// ---------------- GEMM core (triple-buffered, counted vmcnt, 16x16 frags): C = A[M,K]*BT[N,K]^T ----------------
// 16x16 fragment LDS read = 16 rows x 4 col-slots = all 64 16B-slots of a contiguous 1KB
// region -> uniform across all 8 bank groups (bandwidth-optimal). Do NOT switch to 32x32
// frags without a row-bit-mixing swizzle: that read only touches half the bank groups (R11).
template<int BM, int BN>
__device__ __forceinline__ void gemm_core(const unsigned short* __restrict__ A,
                                          const unsigned short* __restrict__ BT,
                                          int m0, int n0,
                                          unsigned short* As, unsigned short* Bs,
                                          f32x4 (&acc)[BM / 32][BN / 32]) {
  const int t = threadIdx.x, w = t >> 6, l = t & 63;
  const int lr = l & 15, lg = (l >> 4) * 8;
  const int wm = (w >> 1) * (BM / 2), wn = (w & 1) * (BN / 2);
  constexpr int K = 1024;
  constexpr int AI = BM / 64, BI = BN / 64, NLD = AI + BI;

#define GSTAGE(buf, k0) do {                                                               \
    _Pragma("unroll")                                                                      \
    for (int it_ = 0; it_ < AI; ++it_) {                                                   \
      int o_ = t * 16 + it_ * 4096;                                                        \
      int row_ = o_ >> 6, ce_ = (o_ & 63) >> 1;                                            \
      gload_lds16(A + (size_t)(m0 + row_) * K + (k0) + ce_,                                \
                  (char*)As + (buf) * (BM * 64) + it_ * 4096 + w * 1024);                  \
    }                                                                                      \
    _Pragma("unroll")                                                                      \
    for (int it_ = 0; it_ < BI; ++it_) {                                                   \
      int o_ = t * 16 + it_ * 4096;                                                        \
      int row_ = o_ >> 6, ce_ = (o_ & 63) >> 1;                                            \
      gload_lds16(BT + (size_t)(n0 + row_) * K + (k0) + ce_,                               \
                  (char*)Bs + (buf) * (BN * 64) + it_ * 4096 + w * 1024);                  \
    }                                                                                      \
  } while (0)

  GSTAGE(0, 0);
  GSTAGE(1, 32);
  if constexpr (NLD == 4) VM_BARRIER(4); else VM_BARRIER(3);
  int cur = 0;
  for (int kt = 0; kt < 32; ++kt) {
    int nb = cur + 2; if (nb >= 3) nb -= 3;
    if (kt < 30) GSTAGE(nb, (kt + 2) * 32);
    bf16x8 af[BM / 32], bfr[BN / 32];
#pragma unroll
    for (int mi = 0; mi < BM / 32; ++mi)
      af[mi] = *(const bf16x8*)&As[cur * (BM * 32) + (wm + mi * 16 + lr) * 32 + lg];
#pragma unroll
    for (int ni = 0; ni < BN / 32; ++ni)
      bfr[ni] = *(const bf16x8*)&Bs[cur * (BN * 32) + (wn + ni * 16 + lr) * 32 + lg];
    __builtin_amdgcn_s_setprio(1);
#pragma unroll
    for (int mi = 0; mi < BM / 32; ++mi)
#pragma unroll
      for (int ni = 0; ni < BN / 32; ++ni)
        acc[mi][ni] = __builtin_amdgcn_mfma_f32_16x16x32_bf16(af[mi], bfr[ni], acc[mi][ni], 0, 0, 0);
    __builtin_amdgcn_s_setprio(0);
    if (kt < 30) { if constexpr (NLD == 4) VM_BARRIER(4); else VM_BARRIER(3); }
    else if (kt == 30) VM_BARRIER(0);
    cur = (cur == 2) ? 0 : cur + 1;
  }
#undef GSTAGE
}

// ---------------- fused QKV projection (768 blocks, 3/CU) ----------------
// z=0: qp = (qb*WqT^T)*scale*log2e; z=1: kp = cb*WkT^T; z=2: vt = WvT*cb^T = V^T
__global__ __launch_bounds__(256) void gemm_qkv(const unsigned short* __restrict__ qb,
                                                const unsigned short* __restrict__ cb,
                                                const unsigned short* __restrict__ WqT,
                                                const unsigned short* __restrict__ WkT,
                                                const unsigned short* __restrict__ WvT,
                                                unsigned short* __restrict__ qp,
                                                unsigned short* __restrict__ kp,
                                                unsigned short* __restrict__ vt) {
  __shared__ unsigned short As[3 * 4096];
  __shared__ unsigned short Bs[3 * 4096];
  int wg = (blockIdx.x & 7) * 96 + (blockIdx.x >> 3);  // XCD swizzle (768 % 8 == 0)
  int z = wg >> 8, r = wg & 255;
  const unsigned short *A, *BT; unsigned short* C; int N, bx, by;
  float osc;
  if (z == 0)      { A = qb;  BT = WqT; C = qp; N = 1024; bx = r & 31; by = r >> 5; osc = 0.125f * 1.44269504089f; }
  else if (z == 1) { A = cb;  BT = WkT; C = kp; N = 1024; bx = r & 31; by = r >> 5; osc = 1.f; }
  else             { A = WvT; BT = cb;  C = vt; N = 4096; bx = r & 7;  by = r >> 3; osc = 1.f; }
  f32x4 acc[4][4];
#pragma unroll
  for (int mi = 0; mi < 4; ++mi)
#pragma unroll
    for (int ni = 0; ni < 4; ++ni) acc[mi][ni] = {0.f, 0.f, 0.f, 0.f};
  gemm_core<128, 128>(A, BT, bx * 128, by * 128, As, Bs, acc);
  const int t = threadIdx.x, w = t >> 6, l = t & 63;
  const int lr = l & 15, lg4 = (l >> 4) * 4;
  const int wm = (w >> 1) * 64, wn = (w & 1) * 64;
#pragma unroll
  for (int mi = 0; mi < 4; ++mi)
#pragma unroll
    for (int ni = 0; ni < 4; ++ni)
#pragma unroll
      for (int j = 0; j < 4; ++j)
        C[(size_t)(bx * 128 + wm + mi * 16 + lg4 + j) * N + by * 128 + wn + ni * 16 + lr] =
            f2bf(acc[mi][ni][j] * osc);
}

// ---------------- final projection: out = ao*WoT^T + bo (fp32), 128x64 tiles ----------------
__global__ __launch_bounds__(256) void gemm_out(const unsigned short* __restrict__ A,
                                                const unsigned short* __restrict__ BT,
                                                const float* __restrict__ bias,
                                                float* __restrict__ C) {
  __shared__ unsigned short As[3 * 4096];
  __shared__ unsigned short Bs[3 * 2048];
  int wg = (blockIdx.x & 7) * 64 + (blockIdx.x >> 3);  // 512 blocks, XCD swizzle
  int by = wg & 15, bx = wg >> 4;
  f32x4 acc[4][2];
#pragma unroll
  for (int mi = 0; mi < 4; ++mi)
#pragma unroll
    for (int ni = 0; ni < 2; ++ni) acc[mi][ni] = {0.f, 0.f, 0.f, 0.f};
  gemm_core<128, 64>(A, BT, bx * 128, by * 64, As, Bs, acc);
  const int t = threadIdx.x, w = t >> 6, l = t & 63;
  const int lr = l & 15, lg4 = (l >> 4) * 4;
  const int wm = (w >> 1) * 64, wn = (w & 1) * 32;
#pragma unroll
  for (int mi = 0; mi < 4; ++mi)
#pragma unroll
    for (int ni = 0; ni < 2; ++ni) {
      int col = by * 64 + wn + ni * 16 + lr;
      float bv = bias[col];
#pragma unroll
      for (int j = 0; j < 4; ++j)
        C[(size_t)(bx * 128 + wm + mi * 16 + lg4 + j) * 1024 + col] = acc[mi][ni][j] + bv;
    }
}

// ---------------- flash attention, KV-split-2, 32x32x16, ILP-restructured ----------------
// grid 1024 (XCD-grouped); block 256 = 4 waves; each block does HALF the KV range.
// __launch_bounds__(256,4): <=128 regs -> 4 waves/SIMD. K AND V staged to LDS (dbuf) --
// direct-from-global V puts L2 latency on the PV MFMA critical path (R10: -66%).
// ILP: both 32-kv QK^T chains interleaved (s0/s1 alternate -> MFMA pipe fed without
// 4-deep dependent stalls); exp2(s1) slides under PV(s0) MFMA clusters (separate pipes
// co-schedule, m114). Row-sum l on the MFMA pipe via ones-row trick; bare v_exp_f32.
__global__ __launch_bounds__(256, 4) void attn_kernel(const unsigned short* __restrict__ Q,
                                                      const unsigned short* __restrict__ Kp,
                                                      const unsigned short* __restrict__ Vt,
                                                      unsigned short* __restrict__ Op0,
                                                      unsigned short* __restrict__ Op1,
                                                      float* __restrict__ Lp) {
  __shared__ char lds[32768];  // [2 bufs][K 8KB | Vt 8KB]
  const int t = threadIdx.x, w = t >> 6, l = t & 63;
  const int l31 = l & 31, hi = l >> 5;
  const int u = (blockIdx.x & 7) * 128 + (blockIdx.x >> 3);
  const int half = u >> 9, nf = u & 511;
  const int qt = nf & 15, h = (nf >> 4) & 15, b = nf >> 8;

  const int q = qt * 128 + w * 32 + l31;
  const size_t qbase = ((size_t)(b * S_ + q)) * 1024 + h * 64;
  bf16x8 qf[4];  // B-frag: Q[q][k = c*16 + hi*8 + e]
#pragma unroll
  for (int c = 0; c < 4; ++c) qf[c] = *(const bf16x8*)&Q[qbase + c * 16 + hi * 8];

  // ones A-fragment for the l-sum MFMA (bf16 1.0 = 0x3F80)
  union { unsigned short s[8]; bf16x8 v; } ones;
#pragma unroll
  for (int i = 0; i < 8; ++i) ones.s[i] = 0x3F80;

  // K: [s][1024]; Vt: [1024][4096] (col = b*2048 + s); half offsets baked in
  const size_t kbase = (size_t)b * S_ * 1024 + h * 64 + ((size_t)half << 20);
  const size_t vtb = (size_t)(h * 64) * 4096 + (size_t)b * 2048 + half * 1024;

  f32x16 oacc[2];  // O^T[dh][q = l31], unnormalized
  f32x16 lacc;     // row-sum accumulator (all rows identical)
#pragma unroll
  for (int r = 0; r < 16; ++r) { oacc[0][r] = 0.f; oacc[1][r] = 0.f; lacc[r] = 0.f; }

#define STAGE(bsel, kv0) do {                                                          \
    char* kdst = lds + (bsel) * 16384;                                                 \
    char* vdst = kdst + 8192;                                                          \
    _Pragma("unroll")                                                                  \
    for (int it_ = 0; it_ < 2; ++it_) {                                                \
      const int off_ = it_ * 4096 + w * 1024 + l * 16;                                 \
      const int row_ = off_ >> 7, cb_ = off_ & 127;                                    \
      const int sc_ = (cb_ ^ ((row_ & 7) << 4)) >> 1;                                  \
      gload_lds16(Kp + kbase + (size_t)((kv0) + row_) * 1024 + sc_,                    \
                  kdst + it_ * 4096 + w * 1024);                                       \
      gload_lds16(Vt + vtb + (size_t)row_ * 4096 + (kv0) + sc_,                        \
                  vdst + it_ * 4096 + w * 1024);                                       \
    }                                                                                  \
  } while (0)

// pack 8 exp'd scores (rows r0..r0+7 of sv) into the PV B-frag layout
#define PACK(sv, r0, pf) do {                                                          \
    unsigned a_ = cvt_pk_bf16(sv[(r0) + 0], sv[(r0) + 1]);                             \
    unsigned b_ = cvt_pk_bf16(sv[(r0) + 2], sv[(r0) + 3]);                             \
    unsigned c_ = cvt_pk_bf16(sv[(r0) + 4], sv[(r0) + 5]);                             \
    unsigned d_ = cvt_pk_bf16(sv[(r0) + 6], sv[(r0) + 7]);                             \
    asm("v_permlane32_swap_b32 %0, %1" : "+v"(a_), "+v"(c_));                          \
    asm("v_permlane32_swap_b32 %0, %1" : "+v"(b_), "+v"(d_));                          \
    pf.u[0] = a_; pf.u[1] = b_; pf.u[2] = c_; pf.u[3] = d_;                            \
  } while (0)

// PV for 16-kv chunk cc using B-frag pf (3 MFMAs: oacc[0], oacc[1], lacc)
#define PV(cc, pf) do {                                                                \
    bf16x8 vf0_ = *(const bf16x8*)(vb + l31 * 128 + (((cc) * 32 + hi * 16) ^ sw));     \
    bf16x8 vf1_ = *(const bf16x8*)(vb + (32 + l31) * 128 + (((cc) * 32 + hi * 16) ^ sw)); \
    oacc[0] = __builtin_amdgcn_mfma_f32_32x32x16_bf16(vf0_, pf.v, oacc[0], 0, 0, 0);   \
    oacc[1] = __builtin_amdgcn_mfma_f32_32x32x16_bf16(vf1_, pf.v, oacc[1], 0, 0, 0);   \
    lacc = __builtin_amdgcn_mfma_f32_32x32x16_bf16(ones.v, pf.v, lacc, 0, 0, 0);       \
  } while (0)

  STAGE(0, 0);
  VM_BARRIER(0);
  int cur = 0;
  const int sw = (l & 7) << 4;
  union PFU { unsigned u[4]; bf16x8 v; };

  for (int tile = 0; tile < 16; ++tile) {
    if (tile < 15) STAGE(cur ^ 1, (tile + 1) * 64);
    const char* kb = lds + cur * 16384;
    const char* vb = kb + 8192;

    // QK^T for BOTH 32-kv halves, chains interleaved (s0/s1 independent)
    f32x16 s0, s1;
#pragma unroll
    for (int r = 0; r < 16; ++r) { s0[r] = 0.f; s1[r] = 0.f; }
    __builtin_amdgcn_s_setprio(1);
#pragma unroll
    for (int c = 0; c < 4; ++c) {
      bf16x8 kf0 = *(const bf16x8*)(kb + l31 * 128 + ((c * 32 + hi * 16) ^ sw));
      bf16x8 kf1 = *(const bf16x8*)(kb + (32 + l31) * 128 + ((c * 32 + hi * 16) ^ sw));
      s0 = __builtin_amdgcn_mfma_f32_32x32x16_bf16(kf0, qf[c], s0, 0, 0, 0);
      s1 = __builtin_amdgcn_mfma_f32_32x32x16_bf16(kf1, qf[c], s1, 0, 0, 0);
    }
    __builtin_amdgcn_s_setprio(0);

    // exp2(s0), then PV(s0 chunks) with exp2(s1) slid under the MFMA clusters
#pragma unroll
    for (int r = 0; r < 16; ++r) s0[r] = __builtin_amdgcn_exp2f(s0[r]);

    PFU pf;
    PACK(s0, 0, pf);
    __builtin_amdgcn_s_setprio(1);
    PV(0, pf);
    __builtin_amdgcn_s_setprio(0);
#pragma unroll
    for (int r = 0; r < 8; ++r) s1[r] = __builtin_amdgcn_exp2f(s1[r]);
    PACK(s0, 8, pf);
    __builtin_amdgcn_s_setprio(1);
    PV(1, pf);
    __builtin_amdgcn_s_setprio(0);
#pragma unroll
    for (int r = 8; r < 16; ++r) s1[r] = __builtin_amdgcn_exp2f(s1[r]);
    PACK(s1, 0, pf);
    __builtin_amdgcn_s_setprio(1);
    PV(2, pf);
    __builtin_amdgcn_s_setprio(0);
    PACK(s1, 8, pf);
    __builtin_amdgcn_s_setprio(1);
    PV(3, pf);
    __builtin_amdgcn_s_setprio(0);

    if (tile < 15) VM_BARRIER(0);
    cur ^= 1;
  }

  // epilogue: write unnormalized O partial (bf16) + l (fp32)
  unsigned short* Op = half ? Op1 : Op0;
#pragma unroll
  for (int d = 0; d < 2; ++d)
#pragma unroll
    for (int rg = 0; rg < 4; ++rg) {
      ushort4 o4;
      o4.x = f2bf(oacc[d][rg * 4 + 0]);
      o4.y = f2bf(oacc[d][rg * 4 + 1]);
      o4.z = f2bf(oacc[d][rg * 4 + 2]);
      o4.w = f2bf(oacc[d][rg * 4 + 3]);
      *(ushort4*)&Op[qbase + d * 32 + rg * 8 + hi * 4] = o4;
    }
  if (!hi) Lp[half * 65536 + (b * 16 + h) * 2048 + q] = lacc[0];
#undef STAGE
#undef PACK
#undef PV
}

// ---------------- combine: ao = (Oa + Ob) / (la + lb), in place over Op0 ----------------
__global__ __launch_bounds__(256) void combine_kernel(unsigned short* __restrict__ Op0,
                                                      const unsigned short* __restrict__ Op1,
                                                      const float* __restrict__ Lp) {
  int e8 = blockIdx.x * 256 + threadIdx.x;       // 524288 total
  int r = e8 >> 7, c = (e8 & 127) * 8;
  int b = r >> 11, s = r & 2047, h = c >> 6;
  float la = Lp[(b * 16 + h) * 2048 + s];
  float lb = Lp[65536 + (b * 16 + h) * 2048 + s];
  float inv = 1.f / (la + lb);
  size_t off = (size_t)r * 1024 + c;
  ushort4 a0 = *(ushort4*)&Op0[off], a1 = *(ushort4*)&Op0[off + 4];
  ushort4 b0 = *(const ushort4*)&Op1[off], b1 = *(const ushort4*)&Op1[off + 4];
  ushort4 o0, o1;
  o0.x = f2bf((bf2f(a0.x) + bf2f(b0.x)) * inv);
  o0.y = f2bf((bf2f(a0.y) + bf2f(b0.y)) * inv);
  o0.z = f2bf((bf2f(a0.z) + bf2f(b0.z)) * inv);
  o0.w = f2bf((bf2f(a0.w) + bf2f(b0.w)) * inv);
  o1.x = f2bf((bf2f(a1.x) + bf2f(b1.x)) * inv);
  o1.y = f2bf((bf2f(a1.y) + bf2f(b1.y)) * inv);
  o1.z = f2bf((bf2f(a1.z) + bf2f(b1.z)) * inv);
  o1.w = f2bf((bf2f(a1.w) + bf2f(b1.w)) * inv);
  *(ushort4*)&Op0[off] = o0;
  *(ushort4*)&Op0[off + 4] = o1;
}

extern "C" void kernel_launch(void* const* d_in, const int* in_sizes, int n_in,
                              void* d_out, int out_size, void* d_ws, size_t ws_size,
                              hipStream_t stream) {
  const float* query   = (const float*)d_in[0];
  const float* context = (const float*)d_in[1];
  const float* Wq = (const float*)d_in[2];
  const float* Wk = (const float*)d_in[3];
  const float* Wv = (const float*)d_in[4];
  const float* Wo = (const float*)d_in[5];
  const float* bo = (const float*)d_in[6];
  float* out = (float*)d_out;

  const size_t NA = (size_t)B_ * S_ * D_;  // 4 Mi elems
  const size_t NW = (size_t)D_ * D_;       // 1 Mi elems
  unsigned short* ws  = (unsigned short*)d_ws;
  unsigned short* qb  = ws;                // 8 MiB; later Op0 -> ao (in-place combine)
  unsigned short* cb  = qb + NA;           // 8 MiB; later Op1
  unsigned short* WqT = cb + NA;           // 2 MiB; later Lp (512 KiB)
  unsigned short* WkT = WqT + NW;
  unsigned short* WvT = WkT + NW;
  unsigned short* WoT = WvT + NW;
  unsigned short* qp  = WoT + NW;
  unsigned short* kp  = qp + NA;
  unsigned short* vt  = kp + NA;           // V^T [1024][4096]
  unsigned short* Op0 = qb;                // attn partial, half 0 (dead region)
  unsigned short* Op1 = cb;                // attn partial, half 1 (dead region)
  float* Lp = (float*)WqT;                 // row-sums, 2 x 65536 fp32 (dead region)
  unsigned short* ao  = qb;                // combine output, in place over Op0

  prep_kernel<<<12288, 256, 0, stream>>>(query, context, Wq, Wk, Wv, Wo,
                                         qb, cb, WqT, WkT, WvT, WoT);
  gemm_qkv<<<768, 256, 0, stream>>>(qb, cb, WqT, WkT, WvT, qp, kp, vt);
  attn_kernel<<<1024, 256, 0, stream>>>(qp, kp, vt, Op0, Op1, Lp);
  combine_kernel<<<2048, 256, 0, stream>>>(Op0, Op1, Lp);
  gemm_out<<<512, 256, 0, stream>>>(ao, WoT, bo, out);
}

// Round 14
// 121.460 us; speedup vs baseline: 1.0160x; 1.0160x over previous
//
#include <hip/hip_runtime.h>
#include <hip/hip_bf16.h>

typedef __attribute__((ext_vector_type(8))) short bf16x8;
typedef __attribute__((ext_vector_type(4))) float f32x4;
typedef __attribute__((ext_vector_type(16))) float f32x16;

#define B_ 2
#define S_ 2048
#define D_ 1024
#define H_ 16

__device__ __forceinline__ unsigned short f2bf(float x) {
  unsigned u = __float_as_uint(x);
  unsigned r = (u + 0x7fffu + ((u >> 16) & 1u)) >> 16;
  return (unsigned short)r;
}

__device__ __forceinline__ float bf2f(unsigned short x) {
  return __uint_as_float((unsigned)x << 16);
}

__device__ __forceinline__ unsigned cvt_pk_bf16(float lo, float hi) {
  unsigned r;
  asm("v_cvt_pk_bf16_f32 %0, %1, %2" : "=v"(r) : "v"(lo), "v"(hi));
  return r;
}

__device__ __forceinline__ void gload_lds16(const void* g, void* l) {
  __builtin_amdgcn_global_load_lds((const __attribute__((address_space(1))) void*)g,
                                   (__attribute__((address_space(3))) void*)l, 16, 0, 0);
}

// counted-vmcnt barrier: leave N loads in flight across the barrier (T4).
#define VM_BARRIER(N) do {                                   \
    asm volatile("s_waitcnt vmcnt(" #N ")" ::: "memory");    \
    __builtin_amdgcn_s_barrier();                            \
    __builtin_amdgcn_sched_barrier(0);                       \
  } while (0)

// ---------------- prep: bf16 convert (q, ctx) + 4 weight transposes, one launch ----------------
__global__ __launch_bounds__(256) void prep_kernel(const float* __restrict__ query,
                                                   const float* __restrict__ ctx,
                                                   const float* __restrict__ Wq, const float* __restrict__ Wk,
                                                   const float* __restrict__ Wv, const float* __restrict__ Wo,
                                                   unsigned short* __restrict__ qb, unsigned short* __restrict__ cb,
                                                   unsigned short* __restrict__ WqT, unsigned short* __restrict__ WkT,
                                                   unsigned short* __restrict__ WvT, unsigned short* __restrict__ WoT) {
  __shared__ float tile[32][33];
  int bid = blockIdx.x;
  if (bid < 8192) {
    const float* s = bid < 4096 ? query : ctx;
    unsigned short* d = bid < 4096 ? qb : cb;
    int i = (bid & 4095) * 256 + threadIdx.x;
    float4 v = ((const float4*)s)[i];
    ushort4 o;
    o.x = f2bf(v.x); o.y = f2bf(v.y); o.z = f2bf(v.z); o.w = f2bf(v.w);
    ((ushort4*)d)[i] = o;
    return;
  }
  int tid = bid - 8192;              // 4096 transpose blocks
  int z = tid >> 10, r = tid & 1023;
  const float* W; unsigned short* WT;
  if (z == 0)      { W = Wq; WT = WqT; }
  else if (z == 1) { W = Wk; WT = WkT; }
  else if (z == 2) { W = Wv; WT = WvT; }
  else             { W = Wo; WT = WoT; }
  int r0 = (r >> 5) * 32, c0 = (r & 31) * 32;
  int t = threadIdx.x;
  int lr = t >> 3, lc = (t & 7) * 4;
  float4 v = *(const float4*)&W[(size_t)(r0 + lr) * 1024 + c0 + lc];
  tile[lr][lc + 0] = v.x; tile[lr][lc + 1] = v.y; tile[lr][lc + 2] = v.z; tile[lr][lc + 3] = v.w;
  __syncthreads();
  ushort4 o;
  o.x = f2bf(tile[lc + 0][lr]);
  o.y = f2bf(tile[lc + 1][lr]);
  o.z = f2bf(tile[lc + 2][lr]);
  o.w = f2bf(tile[lc + 3][lr]);
  *(ushort4*)&WT[(size_t)(c0 + lr) * 1024 + r0 + lc] = o;
}

// ---------------- GEMM core (triple-buffered, counted vmcnt, 16x16 frags): C = A[M,K]*BT[N,K]^T ----------------
// 16x16 fragment LDS read = 16 rows x 4 col-slots = all 64 16B-slots of a contiguous 1KB
// region -> uniform across all 8 bank groups (bandwidth-optimal). Do NOT switch to 32x32
// frags without a row-bit-mixing swizzle: that read only touches half the bank groups (R11).
template<int BM, int BN>
__device__ __forceinline__ void gemm_core(const unsigned short* __restrict__ A,
                                          const unsigned short* __restrict__ BT,
                                          int m0, int n0,
                                          unsigned short* As, unsigned short* Bs,
                                          f32x4 (&acc)[BM / 32][BN / 32]) {
  const int t = threadIdx.x, w = t >> 6, l = t & 63;
  const int lr = l & 15, lg = (l >> 4) * 8;
  const int wm = (w >> 1) * (BM / 2), wn = (w & 1) * (BN / 2);
  constexpr int K = 1024;
  constexpr int AI = BM / 64, BI = BN / 64, NLD = AI + BI;

#define GSTAGE(buf, k0) do {                                                               \
    _Pragma("unroll")                                                                      \
    for (int it_ = 0; it_ < AI; ++it_) {                                                   \
      int o_ = t * 16 + it_ * 4096;                                                        \
      int row_ = o_ >> 6, ce_ = (o_ & 63) >> 1;                                            \
      gload_lds16(A + (size_t)(m0 + row_) * K + (k0) + ce_,                                \
                  (char*)As + (buf) * (BM * 64) + it_ * 4096 + w * 1024);                  \
    }                                                                                      \
    _Pragma("unroll")                                                                      \
    for (int it_ = 0; it_ < BI; ++it_) {                                                   \
      int o_ = t * 16 + it_ * 4096;                                                        \
      int row_ = o_ >> 6, ce_ = (o_ & 63) >> 1;                                            \
      gload_lds16(BT + (size_t)(n0 + row_) * K + (k0) + ce_,                               \
                  (char*)Bs + (buf) * (BN * 64) + it_ * 4096 + w * 1024);                  \
    }                                                                                      \
  } while (0)

  GSTAGE(0, 0);
  GSTAGE(1, 32);
  if constexpr (NLD == 4) VM_BARRIER(4); else VM_BARRIER(3);
  int cur = 0;
  for (int kt = 0; kt < 32; ++kt) {
    int nb = cur + 2; if (nb >= 3) nb -= 3;
    if (kt < 30) GSTAGE(nb, (kt + 2) * 32);
    bf16x8 af[BM / 32], bfr[BN / 32];
#pragma unroll
    for (int mi = 0; mi < BM / 32; ++mi)
      af[mi] = *(const bf16x8*)&As[cur * (BM * 32) + (wm + mi * 16 + lr) * 32 + lg];
#pragma unroll
    for (int ni = 0; ni < BN / 32; ++ni)
      bfr[ni] = *(const bf16x8*)&Bs[cur * (BN * 32) + (wn + ni * 16 + lr) * 32 + lg];
    __builtin_amdgcn_s_setprio(1);
#pragma unroll
    for (int mi = 0; mi < BM / 32; ++mi)
#pragma unroll
      for (int ni = 0; ni < BN / 32; ++ni)
        acc[mi][ni] = __builtin_amdgcn_mfma_f32_16x16x32_bf16(af[mi], bfr[ni], acc[mi][ni], 0, 0, 0);
    __builtin_amdgcn_s_setprio(0);
    if (kt < 30) { if constexpr (NLD == 4) VM_BARRIER(4); else VM_BARRIER(3); }
    else if (kt == 30) VM_BARRIER(0);
    cur = (cur == 2) ? 0 : cur + 1;
  }
#undef GSTAGE
}

// ---------------- fused QKV projection (768 blocks, 3/CU) ----------------
// z=0: qp = (qb*WqT^T)*scale*log2e; z=1: kp = cb*WkT^T; z=2: vt = WvT*cb^T = V^T
__global__ __launch_bounds__(256) void gemm_qkv(const unsigned short* __restrict__ qb,
                                                const unsigned short* __restrict__ cb,
                                                const unsigned short* __restrict__ WqT,
                                                const unsigned short* __restrict__ WkT,
                                                const unsigned short* __restrict__ WvT,
                                                unsigned short* __restrict__ qp,
                                                unsigned short* __restrict__ kp,
                                                unsigned short* __restrict__ vt) {
  __shared__ unsigned short As[3 * 4096];
  __shared__ unsigned short Bs[3 * 4096];
  int wg = (blockIdx.x & 7) * 96 + (blockIdx.x >> 3);  // XCD swizzle (768 % 8 == 0)
  int z = wg >> 8, r = wg & 255;
  const unsigned short *A, *BT; unsigned short* C; int N, bx, by;
  float osc;
  if (z == 0)      { A = qb;  BT = WqT; C = qp; N = 1024; bx = r & 31; by = r >> 5; osc = 0.125f * 1.44269504089f; }
  else if (z == 1) { A = cb;  BT = WkT; C = kp; N = 1024; bx = r & 31; by = r >> 5; osc = 1.f; }
  else             { A = WvT; BT = cb;  C = vt; N = 4096; bx = r & 7;  by = r >> 3; osc = 1.f; }
  f32x4 acc[4][4];
#pragma unroll
  for (int mi = 0; mi < 4; ++mi)
#pragma unroll
    for (int ni = 0; ni < 4; ++ni) acc[mi][ni] = {0.f, 0.f, 0.f, 0.f};
  gemm_core<128, 128>(A, BT, bx * 128, by * 128, As, Bs, acc);
  const int t = threadIdx.x, w = t >> 6, l = t & 63;
  const int lr = l & 15, lg4 = (l >> 4) * 4;
  const int wm = (w >> 1) * 64, wn = (w & 1) * 64;
#pragma unroll
  for (int mi = 0; mi < 4; ++mi)
#pragma unroll
    for (int ni = 0; ni < 4; ++ni)
#pragma unroll
      for (int j = 0; j < 4; ++j)
        C[(size_t)(bx * 128 + wm + mi * 16 + lg4 + j) * N + by * 128 + wn + ni * 16 + lr] =
            f2bf(acc[mi][ni][j] * osc);
}

// ---------------- final projection: out = ao*WoT^T + bo (fp32), 128x64 tiles ----------------
__global__ __launch_bounds__(256) void gemm_out(const unsigned short* __restrict__ A,
                                                const unsigned short* __restrict__ BT,
                                                const float* __restrict__ bias,
                                                float* __restrict__ C) {
  __shared__ unsigned short As[3 * 4096];
  __shared__ unsigned short Bs[3 * 2048];
  int wg = (blockIdx.x & 7) * 64 + (blockIdx.x >> 3);  // 512 blocks, XCD swizzle
  int by = wg & 15, bx = wg >> 4;
  f32x4 acc[4][2];
#pragma unroll
  for (int mi = 0; mi < 4; ++mi)
#pragma unroll
    for (int ni = 0; ni < 2; ++ni) acc[mi][ni] = {0.f, 0.f, 0.f, 0.f};
  gemm_core<128, 64>(A, BT, bx * 128, by * 64, As, Bs, acc);
  const int t = threadIdx.x, w = t >> 6, l = t & 63;
  const int lr = l & 15, lg4 = (l >> 4) * 4;
  const int wm = (w >> 1) * 64, wn = (w & 1) * 32;
#pragma unroll
  for (int mi = 0; mi < 4; ++mi)
#pragma unroll
    for (int ni = 0; ni < 2; ++ni) {
      int col = by * 64 + wn + ni * 16 + lr;
      float bv = bias[col];
#pragma unroll
      for (int j = 0; j < 4; ++j)
        C[(size_t)(bx * 128 + wm + mi * 16 + lg4 + j) * 1024 + col] = acc[mi][ni][j] + bv;
    }
}

// ---------------- flash attention, KV-split-2, 32x32x16, register-lean (R9/R12-proven 47.9us) ----------------
// grid 1024 (XCD-grouped); block 256 = 4 waves; each block does HALF the KV range.
// __launch_bounds__(256,4): <=128 regs -> 4 waves/SIMD. K AND V staged to LDS (dbuf) --
// direct-from-global V puts L2 latency on the PV MFMA critical path (R10: -66%).
// Serial per-tile body is intentional: intra-wave ILP restructure regressed (R13) --
// inter-wave overlap at 4 waves/SIMD already covers pipe co-issue (m114).
// exp2 via bare v_exp_f32; row-sum l on the MFMA pipe via ones-row trick.
__global__ __launch_bounds__(256, 4) void attn_kernel(const unsigned short* __restrict__ Q,
                                                      const unsigned short* __restrict__ Kp,
                                                      const unsigned short* __restrict__ Vt,
                                                      unsigned short* __restrict__ Op0,
                                                      unsigned short* __restrict__ Op1,
                                                      float* __restrict__ Lp) {
  __shared__ char lds[32768];  // [2 bufs][K 8KB | Vt 8KB]
  const int t = threadIdx.x, w = t >> 6, l = t & 63;
  const int l31 = l & 31, hi = l >> 5;
  const int u = (blockIdx.x & 7) * 128 + (blockIdx.x >> 3);
  const int half = u >> 9, nf = u & 511;
  const int qt = nf & 15, h = (nf >> 4) & 15, b = nf >> 8;

  const int q = qt * 128 + w * 32 + l31;
  const size_t qbase = ((size_t)(b * S_ + q)) * 1024 + h * 64;
  bf16x8 qf[4];  // B-frag: Q[q][k = c*16 + hi*8 + e]
#pragma unroll
  for (int c = 0; c < 4; ++c) qf[c] = *(const bf16x8*)&Q[qbase + c * 16 + hi * 8];

  // ones A-fragment for the l-sum MFMA (bf16 1.0 = 0x3F80)
  union { unsigned short s[8]; bf16x8 v; } ones;
#pragma unroll
  for (int i = 0; i < 8; ++i) ones.s[i] = 0x3F80;

  // K: [s][1024]; Vt: [1024][4096] (col = b*2048 + s); half offsets baked in
  const size_t kbase = (size_t)b * S_ * 1024 + h * 64 + ((size_t)half << 20);
  const size_t vtb = (size_t)(h * 64) * 4096 + (size_t)b * 2048 + half * 1024;

  f32x16 oacc[2];  // O^T[dh][q = l31], unnormalized
  f32x16 lacc;     // row-sum accumulator (all rows identical)
#pragma unroll
  for (int r = 0; r < 16; ++r) { oacc[0][r] = 0.f; oacc[1][r] = 0.f; lacc[r] = 0.f; }

#define STAGE(bsel, kv0) do {                                                          \
    char* kdst = lds + (bsel) * 16384;                                                 \
    char* vdst = kdst + 8192;                                                          \
    _Pragma("unroll")                                                                  \
    for (int it_ = 0; it_ < 2; ++it_) {                                                \
      const int off_ = it_ * 4096 + w * 1024 + l * 16;                                 \
      const int row_ = off_ >> 7, cb_ = off_ & 127;                                    \
      const int sc_ = (cb_ ^ ((row_ & 7) << 4)) >> 1;                                  \
      gload_lds16(Kp + kbase + (size_t)((kv0) + row_) * 1024 + sc_,                    \
                  kdst + it_ * 4096 + w * 1024);                                       \
      gload_lds16(Vt + vtb + (size_t)row_ * 4096 + (kv0) + sc_,                        \
                  vdst + it_ * 4096 + w * 1024);                                       \
    }                                                                                  \
  } while (0)

  STAGE(0, 0);
  VM_BARRIER(0);
  int cur = 0;
  const int sw = (l & 7) << 4;

  for (int tile = 0; tile < 16; ++tile) {
    if (tile < 15) STAGE(cur ^ 1, (tile + 1) * 64);
    const char* kb = lds + cur * 16384;
    const char* vb = kb + 8192;

    // per 32-kv block: S^T -> exp2 -> pack -> PV immediately (16 f32 live)
#pragma unroll
    for (int kvb = 0; kvb < 2; ++kvb) {
      f32x16 sacc;
#pragma unroll
      for (int r = 0; r < 16; ++r) sacc[r] = 0.f;
      const int row = kvb * 32 + l31;
      __builtin_amdgcn_s_setprio(1);
#pragma unroll
      for (int c = 0; c < 4; ++c) {
        bf16x8 kf = *(const bf16x8*)(kb + row * 128 + ((c * 32 + hi * 16) ^ sw));
        sacc = __builtin_amdgcn_mfma_f32_32x32x16_bf16(kf, qf[c], sacc, 0, 0, 0);
      }
      __builtin_amdgcn_s_setprio(0);

#pragma unroll
      for (int r = 0; r < 16; ++r) sacc[r] = __builtin_amdgcn_exp2f(sacc[r]);

      // two 16-kv chunks from this sacc (r0 = 0 then 8)
#pragma unroll
      for (int ch = 0; ch < 2; ++ch) {
        const int c = kvb * 2 + ch, r0 = ch * 8;
        unsigned wA = cvt_pk_bf16(sacc[r0 + 0], sacc[r0 + 1]);
        unsigned wB = cvt_pk_bf16(sacc[r0 + 2], sacc[r0 + 3]);
        unsigned wC = cvt_pk_bf16(sacc[r0 + 4], sacc[r0 + 5]);
        unsigned wD = cvt_pk_bf16(sacc[r0 + 6], sacc[r0 + 7]);
        // (pf0,pf2) = swap(wA,wC): pf0=[wA_lo|wC_lo], pf2=[wA_hi|wC_hi]; same for (wB,wD)
        asm("v_permlane32_swap_b32 %0, %1" : "+v"(wA), "+v"(wC));
        asm("v_permlane32_swap_b32 %0, %1" : "+v"(wB), "+v"(wD));
        union { unsigned u[4]; bf16x8 v; } pf;
        pf.u[0] = wA; pf.u[1] = wB; pf.u[2] = wC; pf.u[3] = wD;
        __builtin_amdgcn_s_setprio(1);
#pragma unroll
        for (int d = 0; d < 2; ++d) {
          const int vrow = d * 32 + l31;
          bf16x8 vf = *(const bf16x8*)(vb + vrow * 128 + ((c * 32 + hi * 16) ^ sw));
          oacc[d] = __builtin_amdgcn_mfma_f32_32x32x16_bf16(vf, pf.v, oacc[d], 0, 0, 0);
        }
        lacc = __builtin_amdgcn_mfma_f32_32x32x16_bf16(ones.v, pf.v, lacc, 0, 0, 0);
        __builtin_amdgcn_s_setprio(0);
      }
    }
    if (tile < 15) VM_BARRIER(0);
    cur ^= 1;
  }

  // epilogue: write unnormalized O partial (bf16) + l (fp32)
  unsigned short* Op = half ? Op1 : Op0;
#pragma unroll
  for (int d = 0; d < 2; ++d)
#pragma unroll
    for (int rg = 0; rg < 4; ++rg) {
      ushort4 o4;
      o4.x = f2bf(oacc[d][rg * 4 + 0]);
      o4.y = f2bf(oacc[d][rg * 4 + 1]);
      o4.z = f2bf(oacc[d][rg * 4 + 2]);
      o4.w = f2bf(oacc[d][rg * 4 + 3]);
      *(ushort4*)&Op[qbase + d * 32 + rg * 8 + hi * 4] = o4;
    }
  if (!hi) Lp[half * 65536 + (b * 16 + h) * 2048 + q] = lacc[0];
#undef STAGE
}

// ---------------- combine: ao = (Oa + Ob) / (la + lb), in place over Op0 ----------------
__global__ __launch_bounds__(256) void combine_kernel(unsigned short* __restrict__ Op0,
                                                      const unsigned short* __restrict__ Op1,
                                                      const float* __restrict__ Lp) {
  int e8 = blockIdx.x * 256 + threadIdx.x;       // 524288 total
  int r = e8 >> 7, c = (e8 & 127) * 8;
  int b = r >> 11, s = r & 2047, h = c >> 6;
  float la = Lp[(b * 16 + h) * 2048 + s];
  float lb = Lp[65536 + (b * 16 + h) * 2048 + s];
  float inv = 1.f / (la + lb);
  size_t off = (size_t)r * 1024 + c;
  ushort4 a0 = *(ushort4*)&Op0[off], a1 = *(ushort4*)&Op0[off + 4];
  ushort4 b0 = *(const ushort4*)&Op1[off], b1 = *(const ushort4*)&Op1[off + 4];
  ushort4 o0, o1;
  o0.x = f2bf((bf2f(a0.x) + bf2f(b0.x)) * inv);
  o0.y = f2bf((bf2f(a0.y) + bf2f(b0.y)) * inv);
  o0.z = f2bf((bf2f(a0.z) + bf2f(b0.z)) * inv);
  o0.w = f2bf((bf2f(a0.w) + bf2f(b0.w)) * inv);
  o1.x = f2bf((bf2f(a1.x) + bf2f(b1.x)) * inv);
  o1.y = f2bf((bf2f(a1.y) + bf2f(b1.y)) * inv);
  o1.z = f2bf((bf2f(a1.z) + bf2f(b1.z)) * inv);
  o1.w = f2bf((bf2f(a1.w) + bf2f(b1.w)) * inv);
  *(ushort4*)&Op0[off] = o0;
  *(ushort4*)&Op0[off + 4] = o1;
}

extern "C" void kernel_launch(void* const* d_in, const int* in_sizes, int n_in,
                              void* d_out, int out_size, void* d_ws, size_t ws_size,
                              hipStream_t stream) {
  const float* query   = (const float*)d_in[0];
  const float* context = (const float*)d_in[1];
  const float* Wq = (const float*)d_in[2];
  const float* Wk = (const float*)d_in[3];
  const float* Wv = (const float*)d_in[4];
  const float* Wo = (const float*)d_in[5];
  const float* bo = (const float*)d_in[6];
  float* out = (float*)d_out;

  const size_t NA = (size_t)B_ * S_ * D_;  // 4 Mi elems
  const size_t NW = (size_t)D_ * D_;       // 1 Mi elems
  unsigned short* ws  = (unsigned short*)d_ws;
  unsigned short* qb  = ws;                // 8 MiB; later Op0 -> ao (in-place combine)
  unsigned short* cb  = qb + NA;           // 8 MiB; later Op1
  unsigned short* WqT = cb + NA;           // 2 MiB; later Lp (512 KiB)
  unsigned short* WkT = WqT + NW;
  unsigned short* WvT = WkT + NW;
  unsigned short* WoT = WvT + NW;
  unsigned short* qp  = WoT + NW;
  unsigned short* kp  = qp + NA;
  unsigned short* vt  = kp + NA;           // V^T [1024][4096]
  unsigned short* Op0 = qb;                // attn partial, half 0 (dead region)
  unsigned short* Op1 = cb;                // attn partial, half 1 (dead region)
  float* Lp = (float*)WqT;                 // row-sums, 2 x 65536 fp32 (dead region)
  unsigned short* ao  = qb;                // combine output, in place over Op0

  prep_kernel<<<12288, 256, 0, stream>>>(query, context, Wq, Wk, Wv, Wo,
                                         qb, cb, WqT, WkT, WvT, WoT);
  gemm_qkv<<<768, 256, 0, stream>>>(qb, cb, WqT, WkT, WvT, qp, kp, vt);
  attn_kernel<<<1024, 256, 0, stream>>>(qp, kp, vt, Op0, Op1, Lp);
  combine_kernel<<<2048, 256, 0, stream>>>(Op0, Op1, Lp);
  gemm_out<<<512, 256, 0, stream>>>(ao, WoT, bo, out);
}

// Round 15
// 119.987 us; speedup vs baseline: 1.0285x; 1.0123x over previous
//
#include <hip/hip_runtime.h>
#include <hip/hip_bf16.h>

typedef __attribute__((ext_vector_type(8))) short bf16x8;
typedef __attribute__((ext_vector_type(4))) float f32x4;
typedef __attribute__((ext_vector_type(16))) float f32x16;

#define B_ 2
#define S_ 2048
#define D_ 1024
#define H_ 16

__device__ __forceinline__ unsigned short f2bf(float x) {
  unsigned u = __float_as_uint(x);
  unsigned r = (u + 0x7fffu + ((u >> 16) & 1u)) >> 16;
  return (unsigned short)r;
}

__device__ __forceinline__ float bf2f(unsigned short x) {
  return __uint_as_float((unsigned)x << 16);
}

__device__ __forceinline__ unsigned cvt_pk_bf16(float lo, float hi) {
  unsigned r;
  asm("v_cvt_pk_bf16_f32 %0, %1, %2" : "=v"(r) : "v"(lo), "v"(hi));
  return r;
}

__device__ __forceinline__ void gload_lds16(const void* g, void* l) {
  __builtin_amdgcn_global_load_lds((const __attribute__((address_space(1))) void*)g,
                                   (__attribute__((address_space(3))) void*)l, 16, 0, 0);
}

// counted-vmcnt barrier: leave N loads in flight across the barrier (T4).
#define VM_BARRIER(N) do {                                   \
    asm volatile("s_waitcnt vmcnt(" #N ")" ::: "memory");    \
    __builtin_amdgcn_s_barrier();                            \
    __builtin_amdgcn_sched_barrier(0);                       \
  } while (0)

// ---------------- prep: bf16 convert (q, ctx) + 4 weight transposes, one launch ----------------
__global__ __launch_bounds__(256) void prep_kernel(const float* __restrict__ query,
                                                   const float* __restrict__ ctx,
                                                   const float* __restrict__ Wq, const float* __restrict__ Wk,
                                                   const float* __restrict__ Wv, const float* __restrict__ Wo,
                                                   unsigned short* __restrict__ qb, unsigned short* __restrict__ cb,
                                                   unsigned short* __restrict__ WqT, unsigned short* __restrict__ WkT,
                                                   unsigned short* __restrict__ WvT, unsigned short* __restrict__ WoT) {
  __shared__ float tile[32][33];
  int bid = blockIdx.x;
  if (bid < 8192) {
    const float* s = bid < 4096 ? query : ctx;
    unsigned short* d = bid < 4096 ? qb : cb;
    int i = (bid & 4095) * 256 + threadIdx.x;
    float4 v = ((const float4*)s)[i];
    ushort4 o;
    o.x = f2bf(v.x); o.y = f2bf(v.y); o.z = f2bf(v.z); o.w = f2bf(v.w);
    ((ushort4*)d)[i] = o;
    return;
  }
  int tid = bid - 8192;              // 4096 transpose blocks
  int z = tid >> 10, r = tid & 1023;
  const float* W; unsigned short* WT;
  if (z == 0)      { W = Wq; WT = WqT; }
  else if (z == 1) { W = Wk; WT = WkT; }
  else if (z == 2) { W = Wv; WT = WvT; }
  else             { W = Wo; WT = WoT; }
  int r0 = (r >> 5) * 32, c0 = (r & 31) * 32;
  int t = threadIdx.x;
  int lr = t >> 3, lc = (t & 7) * 4;
  float4 v = *(const float4*)&W[(size_t)(r0 + lr) * 1024 + c0 + lc];
  tile[lr][lc + 0] = v.x; tile[lr][lc + 1] = v.y; tile[lr][lc + 2] = v.z; tile[lr][lc + 3] = v.w;
  __syncthreads();
  ushort4 o;
  o.x = f2bf(tile[lc + 0][lr]);
  o.y = f2bf(tile[lc + 1][lr]);
  o.z = f2bf(tile[lc + 2][lr]);
  o.w = f2bf(tile[lc + 3][lr]);
  *(ushort4*)&WT[(size_t)(c0 + lr) * 1024 + r0 + lc] = o;
}

// ---------------- GEMM core (triple-buffered, counted vmcnt, 16x16 frags): C = A[M,K]*BT[N,K]^T ----------------
// 16x16 fragment LDS read = 16 rows x 4 col-slots = all 64 16B-slots of a contiguous 1KB
// region -> uniform across all 8 bank groups (bandwidth-optimal). Do NOT switch to 32x32
// frags without a row-bit-mixing swizzle: that read only touches half the bank groups (R11).
template<int BM, int BN>
__device__ __forceinline__ void gemm_core(const unsigned short* __restrict__ A,
                                          const unsigned short* __restrict__ BT,
                                          int m0, int n0,
                                          unsigned short* As, unsigned short* Bs,
                                          f32x4 (&acc)[BM / 32][BN / 32]) {
  const int t = threadIdx.x, w = t >> 6, l = t & 63;
  const int lr = l & 15, lg = (l >> 4) * 8;
  const int wm = (w >> 1) * (BM / 2), wn = (w & 1) * (BN / 2);
  constexpr int K = 1024;
  constexpr int AI = BM / 64, BI = BN / 64, NLD = AI + BI;

#define GSTAGE(buf, k0) do {                                                               \
    _Pragma("unroll")                                                                      \
    for (int it_ = 0; it_ < AI; ++it_) {                                                   \
      int o_ = t * 16 + it_ * 4096;                                                        \
      int row_ = o_ >> 6, ce_ = (o_ & 63) >> 1;                                            \
      gload_lds16(A + (size_t)(m0 + row_) * K + (k0) + ce_,                                \
                  (char*)As + (buf) * (BM * 64) + it_ * 4096 + w * 1024);                  \
    }                                                                                      \
    _Pragma("unroll")                                                                      \
    for (int it_ = 0; it_ < BI; ++it_) {                                                   \
      int o_ = t * 16 + it_ * 4096;                                                        \
      int row_ = o_ >> 6, ce_ = (o_ & 63) >> 1;                                            \
      gload_lds16(BT + (size_t)(n0 + row_) * K + (k0) + ce_,                               \
                  (char*)Bs + (buf) * (BN * 64) + it_ * 4096 + w * 1024);                  \
    }                                                                                      \
  } while (0)

  GSTAGE(0, 0);
  GSTAGE(1, 32);
  if constexpr (NLD == 4) VM_BARRIER(4); else VM_BARRIER(3);
  int cur = 0;
  for (int kt = 0; kt < 32; ++kt) {
    int nb = cur + 2; if (nb >= 3) nb -= 3;
    if (kt < 30) GSTAGE(nb, (kt + 2) * 32);
    bf16x8 af[BM / 32], bfr[BN / 32];
#pragma unroll
    for (int mi = 0; mi < BM / 32; ++mi)
      af[mi] = *(const bf16x8*)&As[cur * (BM * 32) + (wm + mi * 16 + lr) * 32 + lg];
#pragma unroll
    for (int ni = 0; ni < BN / 32; ++ni)
      bfr[ni] = *(const bf16x8*)&Bs[cur * (BN * 32) + (wn + ni * 16 + lr) * 32 + lg];
    __builtin_amdgcn_s_setprio(1);
#pragma unroll
    for (int mi = 0; mi < BM / 32; ++mi)
#pragma unroll
      for (int ni = 0; ni < BN / 32; ++ni)
        acc[mi][ni] = __builtin_amdgcn_mfma_f32_16x16x32_bf16(af[mi], bfr[ni], acc[mi][ni], 0, 0, 0);
    __builtin_amdgcn_s_setprio(0);
    if (kt < 30) { if constexpr (NLD == 4) VM_BARRIER(4); else VM_BARRIER(3); }
    else if (kt == 30) VM_BARRIER(0);
    cur = (cur == 2) ? 0 : cur + 1;
  }
#undef GSTAGE
}

// ---------------- fused QKV projection (768 blocks, 3/CU) ----------------
// z=0: qp = (qb*WqT^T)*scale*log2e; z=1: kp = cb*WkT^T; z=2: vt = WvT*cb^T = V^T
__global__ __launch_bounds__(256) void gemm_qkv(const unsigned short* __restrict__ qb,
                                                const unsigned short* __restrict__ cb,
                                                const unsigned short* __restrict__ WqT,
                                                const unsigned short* __restrict__ WkT,
                                                const unsigned short* __restrict__ WvT,
                                                unsigned short* __restrict__ qp,
                                                unsigned short* __restrict__ kp,
                                                unsigned short* __restrict__ vt) {
  __shared__ unsigned short As[3 * 4096];
  __shared__ unsigned short Bs[3 * 4096];
  int wg = (blockIdx.x & 7) * 96 + (blockIdx.x >> 3);  // XCD swizzle (768 % 8 == 0)
  int z = wg >> 8, r = wg & 255;
  const unsigned short *A, *BT; unsigned short* C; int N, bx, by;
  float osc;
  if (z == 0)      { A = qb;  BT = WqT; C = qp; N = 1024; bx = r & 31; by = r >> 5; osc = 0.125f * 1.44269504089f; }
  else if (z == 1) { A = cb;  BT = WkT; C = kp; N = 1024; bx = r & 31; by = r >> 5; osc = 1.f; }
  else             { A = WvT; BT = cb;  C = vt; N = 4096; bx = r & 7;  by = r >> 3; osc = 1.f; }
  f32x4 acc[4][4];
#pragma unroll
  for (int mi = 0; mi < 4; ++mi)
#pragma unroll
    for (int ni = 0; ni < 4; ++ni) acc[mi][ni] = {0.f, 0.f, 0.f, 0.f};
  gemm_core<128, 128>(A, BT, bx * 128, by * 128, As, Bs, acc);
  const int t = threadIdx.x, w = t >> 6, l = t & 63;
  const int lr = l & 15, lg4 = (l >> 4) * 4;
  const int wm = (w >> 1) * 64, wn = (w & 1) * 64;
#pragma unroll
  for (int mi = 0; mi < 4; ++mi)
#pragma unroll
    for (int ni = 0; ni < 4; ++ni)
#pragma unroll
      for (int j = 0; j < 4; ++j)
        C[(size_t)(bx * 128 + wm + mi * 16 + lg4 + j) * N + by * 128 + wn + ni * 16 + lr] =
            f2bf(acc[mi][ni][j] * osc);
}

// ---------------- final projection: out = ao*WoT^T + bo (fp32), 128x64 tiles ----------------
__global__ __launch_bounds__(256) void gemm_out(const unsigned short* __restrict__ A,
                                                const unsigned short* __restrict__ BT,
                                                const float* __restrict__ bias,
                                                float* __restrict__ C) {
  __shared__ unsigned short As[3 * 4096];
  __shared__ unsigned short Bs[3 * 2048];
  int wg = (blockIdx.x & 7) * 64 + (blockIdx.x >> 3);  // 512 blocks, XCD swizzle
  int by = wg & 15, bx = wg >> 4;
  f32x4 acc[4][2];
#pragma unroll
  for (int mi = 0; mi < 4; ++mi)
#pragma unroll
    for (int ni = 0; ni < 2; ++ni) acc[mi][ni] = {0.f, 0.f, 0.f, 0.f};
  gemm_core<128, 64>(A, BT, bx * 128, by * 64, As, Bs, acc);
  const int t = threadIdx.x, w = t >> 6, l = t & 63;
  const int lr = l & 15, lg4 = (l >> 4) * 4;
  const int wm = (w >> 1) * 64, wn = (w & 1) * 32;
#pragma unroll
  for (int mi = 0; mi < 4; ++mi)
#pragma unroll
    for (int ni = 0; ni < 2; ++ni) {
      int col = by * 64 + wn + ni * 16 + lr;
      float bv = bias[col];
#pragma unroll
      for (int j = 0; j < 4; ++j)
        C[(size_t)(bx * 128 + wm + mi * 16 + lg4 + j) * 1024 + col] = acc[mi][ni][j] + bv;
    }
}

// ---------------- flash attention, KV-split-2, 32x32x16, 8-wave blocks ----------------
// grid 512 (XCD-grouped); block 512 = 8 waves x 32 q-rows = 256 q-rows per block.
// Each staged K/V tile now serves 2x the q-rows of the R12 kernel: staging
// instructions/thread, barriers per q-row, and K/V L2 re-fetch all halve while the
// per-wave tile body (proven 47.9us config) stays byte-identical. 2 blocks/CU x 8
// waves = 4 waves/SIMD (same occupancy as R12). __launch_bounds__(512,4) caps VGPR
// at 128. V stays LDS-staged (R10: direct-from-global V = -66%). Serial per-tile
// body intentional (R13: intra-wave ILP regressed). exp2 = bare v_exp_f32;
// row-sum l on the MFMA pipe via ones-row trick.
__global__ __launch_bounds__(512, 4) void attn_kernel(const unsigned short* __restrict__ Q,
                                                      const unsigned short* __restrict__ Kp,
                                                      const unsigned short* __restrict__ Vt,
                                                      unsigned short* __restrict__ Op0,
                                                      unsigned short* __restrict__ Op1,
                                                      float* __restrict__ Lp) {
  __shared__ char lds[32768];  // [2 bufs][K 8KB | Vt 8KB]
  const int t = threadIdx.x, w = t >> 6, l = t & 63;
  const int l31 = l & 31, hi = l >> 5;
  const int u = (blockIdx.x & 7) * 64 + (blockIdx.x >> 3);  // XCD-grouped (512 = 8*64)
  const int half = u >> 8, nf = u & 255;
  const int qt = nf & 7, h = (nf >> 3) & 15, b = nf >> 7;

  const int q = qt * 256 + w * 32 + l31;
  const size_t qbase = ((size_t)(b * S_ + q)) * 1024 + h * 64;
  bf16x8 qf[4];  // B-frag: Q[q][k = c*16 + hi*8 + e]
#pragma unroll
  for (int c = 0; c < 4; ++c) qf[c] = *(const bf16x8*)&Q[qbase + c * 16 + hi * 8];

  // ones A-fragment for the l-sum MFMA (bf16 1.0 = 0x3F80)
  union { unsigned short s[8]; bf16x8 v; } ones;
#pragma unroll
  for (int i = 0; i < 8; ++i) ones.s[i] = 0x3F80;

  // K: [s][1024]; Vt: [1024][4096] (col = b*2048 + s); half offsets baked in
  const size_t kbase = (size_t)b * S_ * 1024 + h * 64 + ((size_t)half << 20);
  const size_t vtb = (size_t)(h * 64) * 4096 + (size_t)b * 2048 + half * 1024;

  f32x16 oacc[2];  // O^T[dh][q = l31], unnormalized
  f32x16 lacc;     // row-sum accumulator (all rows identical)
#pragma unroll
  for (int r = 0; r < 16; ++r) { oacc[0][r] = 0.f; oacc[1][r] = 0.f; lacc[r] = 0.f; }

  // 512 threads cover the 8KB K tile + 8KB V tile in ONE gload pair per thread
#define STAGE(bsel, kv0) do {                                                          \
    char* kdst = lds + (bsel) * 16384;                                                 \
    char* vdst = kdst + 8192;                                                          \
    const int off_ = w * 1024 + l * 16;                                                \
    const int row_ = off_ >> 7, cb_ = off_ & 127;                                      \
    const int sc_ = (cb_ ^ ((row_ & 7) << 4)) >> 1;                                    \
    gload_lds16(Kp + kbase + (size_t)((kv0) + row_) * 1024 + sc_,                      \
                kdst + w * 1024);                                                      \
    gload_lds16(Vt + vtb + (size_t)row_ * 4096 + (kv0) + sc_,                          \
                vdst + w * 1024);                                                      \
  } while (0)

  STAGE(0, 0);
  VM_BARRIER(0);
  int cur = 0;
  const int sw = (l & 7) << 4;

  for (int tile = 0; tile < 16; ++tile) {
    if (tile < 15) STAGE(cur ^ 1, (tile + 1) * 64);
    const char* kb = lds + cur * 16384;
    const char* vb = kb + 8192;

    // per 32-kv block: S^T -> exp2 -> pack -> PV immediately (16 f32 live)
#pragma unroll
    for (int kvb = 0; kvb < 2; ++kvb) {
      f32x16 sacc;
#pragma unroll
      for (int r = 0; r < 16; ++r) sacc[r] = 0.f;
      const int row = kvb * 32 + l31;
      __builtin_amdgcn_s_setprio(1);
#pragma unroll
      for (int c = 0; c < 4; ++c) {
        bf16x8 kf = *(const bf16x8*)(kb + row * 128 + ((c * 32 + hi * 16) ^ sw));
        sacc = __builtin_amdgcn_mfma_f32_32x32x16_bf16(kf, qf[c], sacc, 0, 0, 0);
      }
      __builtin_amdgcn_s_setprio(0);

#pragma unroll
      for (int r = 0; r < 16; ++r) sacc[r] = __builtin_amdgcn_exp2f(sacc[r]);

      // two 16-kv chunks from this sacc (r0 = 0 then 8)
#pragma unroll
      for (int ch = 0; ch < 2; ++ch) {
        const int c = kvb * 2 + ch, r0 = ch * 8;
        unsigned wA = cvt_pk_bf16(sacc[r0 + 0], sacc[r0 + 1]);
        unsigned wB = cvt_pk_bf16(sacc[r0 + 2], sacc[r0 + 3]);
        unsigned wC = cvt_pk_bf16(sacc[r0 + 4], sacc[r0 + 5]);
        unsigned wD = cvt_pk_bf16(sacc[r0 + 6], sacc[r0 + 7]);
        // (pf0,pf2) = swap(wA,wC): pf0=[wA_lo|wC_lo], pf2=[wA_hi|wC_hi]; same for (wB,wD)
        asm("v_permlane32_swap_b32 %0, %1" : "+v"(wA), "+v"(wC));
        asm("v_permlane32_swap_b32 %0, %1" : "+v"(wB), "+v"(wD));
        union { unsigned u[4]; bf16x8 v; } pf;
        pf.u[0] = wA; pf.u[1] = wB; pf.u[2] = wC; pf.u[3] = wD;
        __builtin_amdgcn_s_setprio(1);
#pragma unroll
        for (int d = 0; d < 2; ++d) {
          const int vrow = d * 32 + l31;
          bf16x8 vf = *(const bf16x8*)(vb + vrow * 128 + ((c * 32 + hi * 16) ^ sw));
          oacc[d] = __builtin_amdgcn_mfma_f32_32x32x16_bf16(vf, pf.v, oacc[d], 0, 0, 0);
        }
        lacc = __builtin_amdgcn_mfma_f32_32x32x16_bf16(ones.v, pf.v, lacc, 0, 0, 0);
        __builtin_amdgcn_s_setprio(0);
      }
    }
    if (tile < 15) VM_BARRIER(0);
    cur ^= 1;
  }

  // epilogue: write unnormalized O partial (bf16) + l (fp32)
  unsigned short* Op = half ? Op1 : Op0;
#pragma unroll
  for (int d = 0; d < 2; ++d)
#pragma unroll
    for (int rg = 0; rg < 4; ++rg) {
      ushort4 o4;
      o4.x = f2bf(oacc[d][rg * 4 + 0]);
      o4.y = f2bf(oacc[d][rg * 4 + 1]);
      o4.z = f2bf(oacc[d][rg * 4 + 2]);
      o4.w = f2bf(oacc[d][rg * 4 + 3]);
      *(ushort4*)&Op[qbase + d * 32 + rg * 8 + hi * 4] = o4;
    }
  if (!hi) Lp[half * 65536 + (b * 16 + h) * 2048 + q] = lacc[0];
#undef STAGE
}

// ---------------- combine: ao = (Oa + Ob) / (la + lb), in place over Op0 ----------------
__global__ __launch_bounds__(256) void combine_kernel(unsigned short* __restrict__ Op0,
                                                      const unsigned short* __restrict__ Op1,
                                                      const float* __restrict__ Lp) {
  int e8 = blockIdx.x * 256 + threadIdx.x;       // 524288 total
  int r = e8 >> 7, c = (e8 & 127) * 8;
  int b = r >> 11, s = r & 2047, h = c >> 6;
  float la = Lp[(b * 16 + h) * 2048 + s];
  float lb = Lp[65536 + (b * 16 + h) * 2048 + s];
  float inv = 1.f / (la + lb);
  size_t off = (size_t)r * 1024 + c;
  ushort4 a0 = *(ushort4*)&Op0[off], a1 = *(ushort4*)&Op0[off + 4];
  ushort4 b0 = *(const ushort4*)&Op1[off], b1 = *(const ushort4*)&Op1[off + 4];
  ushort4 o0, o1;
  o0.x = f2bf((bf2f(a0.x) + bf2f(b0.x)) * inv);
  o0.y = f2bf((bf2f(a0.y) + bf2f(b0.y)) * inv);
  o0.z = f2bf((bf2f(a0.z) + bf2f(b0.z)) * inv);
  o0.w = f2bf((bf2f(a0.w) + bf2f(b0.w)) * inv);
  o1.x = f2bf((bf2f(a1.x) + bf2f(b1.x)) * inv);
  o1.y = f2bf((bf2f(a1.y) + bf2f(b1.y)) * inv);
  o1.z = f2bf((bf2f(a1.z) + bf2f(b1.z)) * inv);
  o1.w = f2bf((bf2f(a1.w) + bf2f(b1.w)) * inv);
  *(ushort4*)&Op0[off] = o0;
  *(ushort4*)&Op0[off + 4] = o1;
}

extern "C" void kernel_launch(void* const* d_in, const int* in_sizes, int n_in,
                              void* d_out, int out_size, void* d_ws, size_t ws_size,
                              hipStream_t stream) {
  const float* query   = (const float*)d_in[0];
  const float* context = (const float*)d_in[1];
  const float* Wq = (const float*)d_in[2];
  const float* Wk = (const float*)d_in[3];
  const float* Wv = (const float*)d_in[4];
  const float* Wo = (const float*)d_in[5];
  const float* bo = (const float*)d_in[6];
  float* out = (float*)d_out;

  const size_t NA = (size_t)B_ * S_ * D_;  // 4 Mi elems
  const size_t NW = (size_t)D_ * D_;       // 1 Mi elems
  unsigned short* ws  = (unsigned short*)d_ws;
  unsigned short* qb  = ws;                // 8 MiB; later Op0 -> ao (in-place combine)
  unsigned short* cb  = qb + NA;           // 8 MiB; later Op1
  unsigned short* WqT = cb + NA;           // 2 MiB; later Lp (512 KiB)
  unsigned short* WkT = WqT + NW;
  unsigned short* WvT = WkT + NW;
  unsigned short* WoT = WvT + NW;
  unsigned short* qp  = WoT + NW;
  unsigned short* kp  = qp + NA;
  unsigned short* vt  = kp + NA;           // V^T [1024][4096]
  unsigned short* Op0 = qb;                // attn partial, half 0 (dead region)
  unsigned short* Op1 = cb;                // attn partial, half 1 (dead region)
  float* Lp = (float*)WqT;                 // row-sums, 2 x 65536 fp32 (dead region)
  unsigned short* ao  = qb;                // combine output, in place over Op0

  prep_kernel<<<12288, 256, 0, stream>>>(query, context, Wq, Wk, Wv, Wo,
                                         qb, cb, WqT, WkT, WvT, WoT);
  gemm_qkv<<<768, 256, 0, stream>>>(qb, cb, WqT, WkT, WvT, qp, kp, vt);
  attn_kernel<<<512, 512, 0, stream>>>(qp, kp, vt, Op0, Op1, Lp);
  combine_kernel<<<2048, 256, 0, stream>>>(Op0, Op1, Lp);
  gemm_out<<<512, 256, 0, stream>>>(ao, WoT, bo, out);
}

// Round 16
// 119.615 us; speedup vs baseline: 1.0317x; 1.0031x over previous
//
#include <hip/hip_runtime.h>
#include <hip/hip_bf16.h>

typedef __attribute__((ext_vector_type(8))) short bf16x8;
typedef __attribute__((ext_vector_type(4))) float f32x4;
typedef __attribute__((ext_vector_type(16))) float f32x16;

#define B_ 2
#define S_ 2048
#define D_ 1024
#define H_ 16

__device__ __forceinline__ unsigned short f2bf(float x) {
  unsigned u = __float_as_uint(x);
  unsigned r = (u + 0x7fffu + ((u >> 16) & 1u)) >> 16;
  return (unsigned short)r;
}

__device__ __forceinline__ float bf2f(unsigned short x) {
  return __uint_as_float((unsigned)x << 16);
}

__device__ __forceinline__ unsigned cvt_pk_bf16(float lo, float hi) {
  unsigned r;
  asm("v_cvt_pk_bf16_f32 %0, %1, %2" : "=v"(r) : "v"(lo), "v"(hi));
  return r;
}

__device__ __forceinline__ void gload_lds16(const void* g, void* l) {
  __builtin_amdgcn_global_load_lds((const __attribute__((address_space(1))) void*)g,
                                   (__attribute__((address_space(3))) void*)l, 16, 0, 0);
}

// counted-vmcnt barrier: leave N loads in flight across the barrier (T4).
#define VM_BARRIER(N) do {                                   \
    asm volatile("s_waitcnt vmcnt(" #N ")" ::: "memory");    \
    __builtin_amdgcn_s_barrier();                            \
    __builtin_amdgcn_sched_barrier(0);                       \
  } while (0)

// ---------------- prep: bf16 convert (q, ctx) + 4 weight transposes, one launch ----------------
__global__ __launch_bounds__(256) void prep_kernel(const float* __restrict__ query,
                                                   const float* __restrict__ ctx,
                                                   const float* __restrict__ Wq, const float* __restrict__ Wk,
                                                   const float* __restrict__ Wv, const float* __restrict__ Wo,
                                                   unsigned short* __restrict__ qb, unsigned short* __restrict__ cb,
                                                   unsigned short* __restrict__ WqT, unsigned short* __restrict__ WkT,
                                                   unsigned short* __restrict__ WvT, unsigned short* __restrict__ WoT) {
  __shared__ float tile[32][33];
  int bid = blockIdx.x;
  if (bid < 8192) {
    const float* s = bid < 4096 ? query : ctx;
    unsigned short* d = bid < 4096 ? qb : cb;
    int i = (bid & 4095) * 256 + threadIdx.x;
    float4 v = ((const float4*)s)[i];
    ushort4 o;
    o.x = f2bf(v.x); o.y = f2bf(v.y); o.z = f2bf(v.z); o.w = f2bf(v.w);
    ((ushort4*)d)[i] = o;
    return;
  }
  int tid = bid - 8192;              // 4096 transpose blocks
  int z = tid >> 10, r = tid & 1023;
  const float* W; unsigned short* WT;
  if (z == 0)      { W = Wq; WT = WqT; }
  else if (z == 1) { W = Wk; WT = WkT; }
  else if (z == 2) { W = Wv; WT = WvT; }
  else             { W = Wo; WT = WoT; }
  int r0 = (r >> 5) * 32, c0 = (r & 31) * 32;
  int t = threadIdx.x;
  int lr = t >> 3, lc = (t & 7) * 4;
  float4 v = *(const float4*)&W[(size_t)(r0 + lr) * 1024 + c0 + lc];
  tile[lr][lc + 0] = v.x; tile[lr][lc + 1] = v.y; tile[lr][lc + 2] = v.z; tile[lr][lc + 3] = v.w;
  __syncthreads();
  ushort4 o;
  o.x = f2bf(tile[lc + 0][lr]);
  o.y = f2bf(tile[lc + 1][lr]);
  o.z = f2bf(tile[lc + 2][lr]);
  o.w = f2bf(tile[lc + 3][lr]);
  *(ushort4*)&WT[(size_t)(c0 + lr) * 1024 + r0 + lc] = o;
}

// ---------------- GEMM core (triple-buffered, counted vmcnt, 16x16 frags): C = A[M,K]*BT[N,K]^T ----------------
// 16x16 fragment LDS read = 16 rows x 4 col-slots = all 64 16B-slots of a contiguous 1KB
// region -> uniform across all 8 bank groups (bandwidth-optimal). Do NOT switch to 32x32
// frags without a row-bit-mixing swizzle: that read only touches half the bank groups (R11).
template<int BM, int BN>
__device__ __forceinline__ void gemm_core(const unsigned short* __restrict__ A,
                                          const unsigned short* __restrict__ BT,
                                          int m0, int n0,
                                          unsigned short* As, unsigned short* Bs,
                                          f32x4 (&acc)[BM / 32][BN / 32]) {
  const int t = threadIdx.x, w = t >> 6, l = t & 63;
  const int lr = l & 15, lg = (l >> 4) * 8;
  const int wm = (w >> 1) * (BM / 2), wn = (w & 1) * (BN / 2);
  constexpr int K = 1024;
  constexpr int AI = BM / 64, BI = BN / 64, NLD = AI + BI;

#define GSTAGE(buf, k0) do {                                                               \
    _Pragma("unroll")                                                                      \
    for (int it_ = 0; it_ < AI; ++it_) {                                                   \
      int o_ = t * 16 + it_ * 4096;                                                        \
      int row_ = o_ >> 6, ce_ = (o_ & 63) >> 1;                                            \
      gload_lds16(A + (size_t)(m0 + row_) * K + (k0) + ce_,                                \
                  (char*)As + (buf) * (BM * 64) + it_ * 4096 + w * 1024);                  \
    }                                                                                      \
    _Pragma("unroll")                                                                      \
    for (int it_ = 0; it_ < BI; ++it_) {                                                   \
      int o_ = t * 16 + it_ * 4096;                                                        \
      int row_ = o_ >> 6, ce_ = (o_ & 63) >> 1;                                            \
      gload_lds16(BT + (size_t)(n0 + row_) * K + (k0) + ce_,                               \
                  (char*)Bs + (buf) * (BN * 64) + it_ * 4096 + w * 1024);                  \
    }                                                                                      \
  } while (0)

  GSTAGE(0, 0);
  GSTAGE(1, 32);
  if constexpr (NLD == 4) VM_BARRIER(4); else VM_BARRIER(3);
  int cur = 0;
  for (int kt = 0; kt < 32; ++kt) {
    int nb = cur + 2; if (nb >= 3) nb -= 3;
    if (kt < 30) GSTAGE(nb, (kt + 2) * 32);
    bf16x8 af[BM / 32], bfr[BN / 32];
#pragma unroll
    for (int mi = 0; mi < BM / 32; ++mi)
      af[mi] = *(const bf16x8*)&As[cur * (BM * 32) + (wm + mi * 16 + lr) * 32 + lg];
#pragma unroll
    for (int ni = 0; ni < BN / 32; ++ni)
      bfr[ni] = *(const bf16x8*)&Bs[cur * (BN * 32) + (wn + ni * 16 + lr) * 32 + lg];
    __builtin_amdgcn_s_setprio(1);
#pragma unroll
    for (int mi = 0; mi < BM / 32; ++mi)
#pragma unroll
      for (int ni = 0; ni < BN / 32; ++ni)
        acc[mi][ni] = __builtin_amdgcn_mfma_f32_16x16x32_bf16(af[mi], bfr[ni], acc[mi][ni], 0, 0, 0);
    __builtin_amdgcn_s_setprio(0);
    if (kt < 30) { if constexpr (NLD == 4) VM_BARRIER(4); else VM_BARRIER(3); }
    else if (kt == 30) VM_BARRIER(0);
    cur = (cur == 2) ? 0 : cur + 1;
  }
#undef GSTAGE
}

// ---------------- fused QKV projection (768 blocks, 3/CU) ----------------
// z=0: qp = (qb*WqT^T)*scale*log2e; z=1: kp = cb*WkT^T; z=2: vt = WvT*cb^T = V^T
__global__ __launch_bounds__(256) void gemm_qkv(const unsigned short* __restrict__ qb,
                                                const unsigned short* __restrict__ cb,
                                                const unsigned short* __restrict__ WqT,
                                                const unsigned short* __restrict__ WkT,
                                                const unsigned short* __restrict__ WvT,
                                                unsigned short* __restrict__ qp,
                                                unsigned short* __restrict__ kp,
                                                unsigned short* __restrict__ vt) {
  __shared__ unsigned short As[3 * 4096];
  __shared__ unsigned short Bs[3 * 4096];
  int wg = (blockIdx.x & 7) * 96 + (blockIdx.x >> 3);  // XCD swizzle (768 % 8 == 0)
  int z = wg >> 8, r = wg & 255;
  const unsigned short *A, *BT; unsigned short* C; int N, bx, by;
  float osc;
  if (z == 0)      { A = qb;  BT = WqT; C = qp; N = 1024; bx = r & 31; by = r >> 5; osc = 0.125f * 1.44269504089f; }
  else if (z == 1) { A = cb;  BT = WkT; C = kp; N = 1024; bx = r & 31; by = r >> 5; osc = 1.f; }
  else             { A = WvT; BT = cb;  C = vt; N = 4096; bx = r & 7;  by = r >> 3; osc = 1.f; }
  f32x4 acc[4][4];
#pragma unroll
  for (int mi = 0; mi < 4; ++mi)
#pragma unroll
    for (int ni = 0; ni < 4; ++ni) acc[mi][ni] = {0.f, 0.f, 0.f, 0.f};
  gemm_core<128, 128>(A, BT, bx * 128, by * 128, As, Bs, acc);
  const int t = threadIdx.x, w = t >> 6, l = t & 63;
  const int lr = l & 15, lg4 = (l >> 4) * 4;
  const int wm = (w >> 1) * 64, wn = (w & 1) * 64;
#pragma unroll
  for (int mi = 0; mi < 4; ++mi)
#pragma unroll
    for (int ni = 0; ni < 4; ++ni)
#pragma unroll
      for (int j = 0; j < 4; ++j)
        C[(size_t)(bx * 128 + wm + mi * 16 + lg4 + j) * N + by * 128 + wn + ni * 16 + lr] =
            f2bf(acc[mi][ni][j] * osc);
}

// ---------------- final projection: out = ao*WoT^T + bo (fp32), 128x64 tiles ----------------
__global__ __launch_bounds__(256) void gemm_out(const unsigned short* __restrict__ A,
                                                const unsigned short* __restrict__ BT,
                                                const float* __restrict__ bias,
                                                float* __restrict__ C) {
  __shared__ unsigned short As[3 * 4096];
  __shared__ unsigned short Bs[3 * 2048];
  int wg = (blockIdx.x & 7) * 64 + (blockIdx.x >> 3);  // 512 blocks, XCD swizzle
  int by = wg & 15, bx = wg >> 4;
  f32x4 acc[4][2];
#pragma unroll
  for (int mi = 0; mi < 4; ++mi)
#pragma unroll
    for (int ni = 0; ni < 2; ++ni) acc[mi][ni] = {0.f, 0.f, 0.f, 0.f};
  gemm_core<128, 64>(A, BT, bx * 128, by * 64, As, Bs, acc);
  const int t = threadIdx.x, w = t >> 6, l = t & 63;
  const int lr = l & 15, lg4 = (l >> 4) * 4;
  const int wm = (w >> 1) * 64, wn = (w & 1) * 32;
#pragma unroll
  for (int mi = 0; mi < 4; ++mi)
#pragma unroll
    for (int ni = 0; ni < 2; ++ni) {
      int col = by * 64 + wn + ni * 16 + lr;
      float bv = bias[col];
#pragma unroll
      for (int j = 0; j < 4; ++j)
        C[(size_t)(bx * 128 + wm + mi * 16 + lg4 + j) * 1024 + col] = acc[mi][ni][j] + bv;
    }
}

// ---------------- flash attention, KV-split-2, 32x32x16, 8-wave blocks, KVBLK=128 ----------------
// grid 512 (XCD-grouped); block 512 = 8 waves x 32 q-rows = 256 q-rows per block.
// KV tile = 128 rows as TWO stacked 64-kv subtiles [K0|K1|V0|V1] x 8KB -- the proven
// 64-kv body runs twice per staged tile with an 8KB base offset (addressing identical).
// Barrier+vmcnt(0) drains halve (15 -> 7). LDS 2 x 32KB = 64KB -> 2 blocks/CU
// (wave-cap-bound 16 waves/CU, same occupancy). V stays LDS-staged (R10);
// serial body intentional (R13); exp2 = bare v_exp_f32; row-sum l on MFMA pipe.
__global__ __launch_bounds__(512, 4) void attn_kernel(const unsigned short* __restrict__ Q,
                                                      const unsigned short* __restrict__ Kp,
                                                      const unsigned short* __restrict__ Vt,
                                                      unsigned short* __restrict__ Op0,
                                                      unsigned short* __restrict__ Op1,
                                                      float* __restrict__ Lp) {
  __shared__ char lds[65536];  // [2 bufs][K0 8K | K1 8K | V0 8K | V1 8K]
  const int t = threadIdx.x, w = t >> 6, l = t & 63;
  const int l31 = l & 31, hi = l >> 5;
  const int u = (blockIdx.x & 7) * 64 + (blockIdx.x >> 3);  // XCD-grouped (512 = 8*64)
  const int half = u >> 8, nf = u & 255;
  const int qt = nf & 7, h = (nf >> 3) & 15, b = nf >> 7;

  const int q = qt * 256 + w * 32 + l31;
  const size_t qbase = ((size_t)(b * S_ + q)) * 1024 + h * 64;
  bf16x8 qf[4];  // B-frag: Q[q][k = c*16 + hi*8 + e]
#pragma unroll
  for (int c = 0; c < 4; ++c) qf[c] = *(const bf16x8*)&Q[qbase + c * 16 + hi * 8];

  // ones A-fragment for the l-sum MFMA (bf16 1.0 = 0x3F80)
  union { unsigned short s[8]; bf16x8 v; } ones;
#pragma unroll
  for (int i = 0; i < 8; ++i) ones.s[i] = 0x3F80;

  // K: [s][1024]; Vt: [1024][4096] (col = b*2048 + s); half offsets baked in
  const size_t kbase = (size_t)b * S_ * 1024 + h * 64 + ((size_t)half << 20);
  const size_t vtb = (size_t)(h * 64) * 4096 + (size_t)b * 2048 + half * 1024;

  f32x16 oacc[2];  // O^T[dh][q = l31], unnormalized
  f32x16 lacc;     // row-sum accumulator (all rows identical)
#pragma unroll
  for (int r = 0; r < 16; ++r) { oacc[0][r] = 0.f; oacc[1][r] = 0.f; lacc[r] = 0.f; }

  // stage 128-kv tile as two 64-kv subtiles; 512 threads: 1 gload per 8KB subtile
#define STAGE(bsel, kv0) do {                                                          \
    char* base = lds + (bsel) * 32768;                                                 \
    const int off_ = w * 1024 + l * 16;                                                \
    const int row_ = off_ >> 7, cb_ = off_ & 127;                                      \
    const int sc_ = (cb_ ^ ((row_ & 7) << 4)) >> 1;                                    \
    _Pragma("unroll")                                                                  \
    for (int sub_ = 0; sub_ < 2; ++sub_) {                                             \
      gload_lds16(Kp + kbase + (size_t)((kv0) + sub_ * 64 + row_) * 1024 + sc_,        \
                  base + sub_ * 8192 + w * 1024);                                      \
      gload_lds16(Vt + vtb + (size_t)row_ * 4096 + (kv0) + sub_ * 64 + sc_,            \
                  base + 16384 + sub_ * 8192 + w * 1024);                              \
    }                                                                                  \
  } while (0)

  STAGE(0, 0);
  VM_BARRIER(0);
  int cur = 0;
  const int sw = (l & 7) << 4;

  for (int tile = 0; tile < 8; ++tile) {
    if (tile < 7) STAGE(cur ^ 1, (tile + 1) * 128);
    const char* tb = lds + cur * 32768;

#pragma unroll
    for (int sub = 0; sub < 2; ++sub) {
      const char* kb = tb + sub * 8192;
      const char* vb = tb + 16384 + sub * 8192;

      // per 32-kv block: S^T -> exp2 -> pack -> PV immediately (16 f32 live)
#pragma unroll
      for (int kvb = 0; kvb < 2; ++kvb) {
        f32x16 sacc;
#pragma unroll
        for (int r = 0; r < 16; ++r) sacc[r] = 0.f;
        const int row = kvb * 32 + l31;
        __builtin_amdgcn_s_setprio(1);
#pragma unroll
        for (int c = 0; c < 4; ++c) {
          bf16x8 kf = *(const bf16x8*)(kb + row * 128 + ((c * 32 + hi * 16) ^ sw));
          sacc = __builtin_amdgcn_mfma_f32_32x32x16_bf16(kf, qf[c], sacc, 0, 0, 0);
        }
        __builtin_amdgcn_s_setprio(0);

#pragma unroll
        for (int r = 0; r < 16; ++r) sacc[r] = __builtin_amdgcn_exp2f(sacc[r]);

        // two 16-kv chunks from this sacc (r0 = 0 then 8)
#pragma unroll
        for (int ch = 0; ch < 2; ++ch) {
          const int c = kvb * 2 + ch, r0 = ch * 8;
          unsigned wA = cvt_pk_bf16(sacc[r0 + 0], sacc[r0 + 1]);
          unsigned wB = cvt_pk_bf16(sacc[r0 + 2], sacc[r0 + 3]);
          unsigned wC = cvt_pk_bf16(sacc[r0 + 4], sacc[r0 + 5]);
          unsigned wD = cvt_pk_bf16(sacc[r0 + 6], sacc[r0 + 7]);
          // (pf0,pf2) = swap(wA,wC); (pf1,pf3) = swap(wB,wD)
          asm("v_permlane32_swap_b32 %0, %1" : "+v"(wA), "+v"(wC));
          asm("v_permlane32_swap_b32 %0, %1" : "+v"(wB), "+v"(wD));
          union { unsigned u[4]; bf16x8 v; } pf;
          pf.u[0] = wA; pf.u[1] = wB; pf.u[2] = wC; pf.u[3] = wD;
          __builtin_amdgcn_s_setprio(1);
#pragma unroll
          for (int d = 0; d < 2; ++d) {
            const int vrow = d * 32 + l31;
            bf16x8 vf = *(const bf16x8*)(vb + vrow * 128 + ((c * 32 + hi * 16) ^ sw));
            oacc[d] = __builtin_amdgcn_mfma_f32_32x32x16_bf16(vf, pf.v, oacc[d], 0, 0, 0);
          }
          lacc = __builtin_amdgcn_mfma_f32_32x32x16_bf16(ones.v, pf.v, lacc, 0, 0, 0);
          __builtin_amdgcn_s_setprio(0);
        }
      }
    }
    if (tile < 7) VM_BARRIER(0);
    cur ^= 1;
  }

  // epilogue: write unnormalized O partial (bf16) + l (fp32)
  unsigned short* Op = half ? Op1 : Op0;
#pragma unroll
  for (int d = 0; d < 2; ++d)
#pragma unroll
    for (int rg = 0; rg < 4; ++rg) {
      ushort4 o4;
      o4.x = f2bf(oacc[d][rg * 4 + 0]);
      o4.y = f2bf(oacc[d][rg * 4 + 1]);
      o4.z = f2bf(oacc[d][rg * 4 + 2]);
      o4.w = f2bf(oacc[d][rg * 4 + 3]);
      *(ushort4*)&Op[qbase + d * 32 + rg * 8 + hi * 4] = o4;
    }
  if (!hi) Lp[half * 65536 + (b * 16 + h) * 2048 + q] = lacc[0];
#undef STAGE
}

// ---------------- combine: ao = (Oa + Ob) / (la + lb), in place over Op0 ----------------
__global__ __launch_bounds__(256) void combine_kernel(unsigned short* __restrict__ Op0,
                                                      const unsigned short* __restrict__ Op1,
                                                      const float* __restrict__ Lp) {
  int e8 = blockIdx.x * 256 + threadIdx.x;       // 524288 total
  int r = e8 >> 7, c = (e8 & 127) * 8;
  int b = r >> 11, s = r & 2047, h = c >> 6;
  float la = Lp[(b * 16 + h) * 2048 + s];
  float lb = Lp[65536 + (b * 16 + h) * 2048 + s];
  float inv = 1.f / (la + lb);
  size_t off = (size_t)r * 1024 + c;
  ushort4 a0 = *(ushort4*)&Op0[off], a1 = *(ushort4*)&Op0[off + 4];
  ushort4 b0 = *(const ushort4*)&Op1[off], b1 = *(const ushort4*)&Op1[off + 4];
  ushort4 o0, o1;
  o0.x = f2bf((bf2f(a0.x) + bf2f(b0.x)) * inv);
  o0.y = f2bf((bf2f(a0.y) + bf2f(b0.y)) * inv);
  o0.z = f2bf((bf2f(a0.z) + bf2f(b0.z)) * inv);
  o0.w = f2bf((bf2f(a0.w) + bf2f(b0.w)) * inv);
  o1.x = f2bf((bf2f(a1.x) + bf2f(b1.x)) * inv);
  o1.y = f2bf((bf2f(a1.y) + bf2f(b1.y)) * inv);
  o1.z = f2bf((bf2f(a1.z) + bf2f(b1.z)) * inv);
  o1.w = f2bf((bf2f(a1.w) + bf2f(b1.w)) * inv);
  *(ushort4*)&Op0[off] = o0;
  *(ushort4*)&Op0[off + 4] = o1;
}

extern "C" void kernel_launch(void* const* d_in, const int* in_sizes, int n_in,
                              void* d_out, int out_size, void* d_ws, size_t ws_size,
                              hipStream_t stream) {
  const float* query   = (const float*)d_in[0];
  const float* context = (const float*)d_in[1];
  const float* Wq = (const float*)d_in[2];
  const float* Wk = (const float*)d_in[3];
  const float* Wv = (const float*)d_in[4];
  const float* Wo = (const float*)d_in[5];
  const float* bo = (const float*)d_in[6];
  float* out = (float*)d_out;

  const size_t NA = (size_t)B_ * S_ * D_;  // 4 Mi elems
  const size_t NW = (size_t)D_ * D_;       // 1 Mi elems
  unsigned short* ws  = (unsigned short*)d_ws;
  unsigned short* qb  = ws;                // 8 MiB; later Op0 -> ao (in-place combine)
  unsigned short* cb  = qb + NA;           // 8 MiB; later Op1
  unsigned short* WqT = cb + NA;           // 2 MiB; later Lp (512 KiB)
  unsigned short* WkT = WqT + NW;
  unsigned short* WvT = WkT + NW;
  unsigned short* WoT = WvT + NW;
  unsigned short* qp  = WoT + NW;
  unsigned short* kp  = qp + NA;
  unsigned short* vt  = kp + NA;           // V^T [1024][4096]
  unsigned short* Op0 = qb;                // attn partial, half 0 (dead region)
  unsigned short* Op1 = cb;                // attn partial, half 1 (dead region)
  float* Lp = (float*)WqT;                 // row-sums, 2 x 65536 fp32 (dead region)
  unsigned short* ao  = qb;                // combine output, in place over Op0

  prep_kernel<<<12288, 256, 0, stream>>>(query, context, Wq, Wk, Wv, Wo,
                                         qb, cb, WqT, WkT, WvT, WoT);
  gemm_qkv<<<768, 256, 0, stream>>>(qb, cb, WqT, WkT, WvT, qp, kp, vt);
  attn_kernel<<<512, 512, 0, stream>>>(qp, kp, vt, Op0, Op1, Lp);
  combine_kernel<<<2048, 256, 0, stream>>>(Op0, Op1, Lp);
  gemm_out<<<512, 256, 0, stream>>>(ao, WoT, bo, out);
}